// Round 1
// 301.411 us; speedup vs baseline: 1.2466x; 1.2466x over previous
//
#include <hip/hip_runtime.h>
#include <hip/hip_bf16.h>

typedef __attribute__((ext_vector_type(4))) float f32x4;
typedef __attribute__((ext_vector_type(8))) short bf16x8;
typedef __attribute__((ext_vector_type(4))) short s16x4;

#define MFMA16(a, b, c) __builtin_amdgcn_mfma_f32_16x16x32_bf16((a), (b), (c), 0, 0, 0)

// ---- LDS layout (bytes) ----
#define W1T_OFF 0        // 128 n-rows x 256 k bf16 (XOR-swizzled chunks of 8) = 65536
#define W2T_OFF 65536    // 64 x 128 bf16 = 16384
#define H1_OFF  81920    // 16 waves x 16 rows x 128 bf16 = 65536 (wave-private)
#define B1_OFF  147456
#define G1_OFF  147968
#define E1_OFF  148480
#define B2_OFF  148992
#define G2_OFF  149248
#define E2_OFF  149504
#define W3_OFF  149760
#define B3_OFF  150016
#define SMEM_BYTES 150048

__device__ __forceinline__ short f2bf(float x) {
  __hip_bfloat16 h = __float2bfloat16(x);
  return __builtin_bit_cast(short, h);
}

__device__ __forceinline__ bf16x8 pack8(f32x4 a, f32x4 b) {
  bf16x8 r;
  r[0] = f2bf(a[0]); r[1] = f2bf(a[1]); r[2] = f2bf(a[2]); r[3] = f2bf(a[3]);
  r[4] = f2bf(b[0]); r[5] = f2bf(b[1]); r[6] = f2bf(b[2]); r[7] = f2bf(b[3]);
  return r;
}

// exact GELU via Abramowitz-Stegun 7.1.26 erf (abs err ~1.5e-7), ~12 VALU ops
__device__ __forceinline__ float gelu_exact(float z) {
  float u = z * 0.70710678118654752440f;
  float a = __builtin_fabsf(u);
  float t = __builtin_amdgcn_rcpf(__builtin_fmaf(0.3275911f, a, 1.0f));
  float p = __builtin_fmaf(t, __builtin_fmaf(t, __builtin_fmaf(t,
              __builtin_fmaf(t, 1.061405429f, -1.453152027f),
              1.421413741f), -0.284496736f), 0.254829592f);
  float e = __expf(-u * u);
  float erfa = __builtin_fmaf(-p * t, e, 1.0f);   // erf(|u|)
  float erfu = (u < 0.0f) ? -erfa : erfa;
  return 0.5f * z * (1.0f + erfu);
}

// Fused gather + (256->128 LN GELU) + (128->64 LN GELU) + (64->1).
// Transposed-GEMM formulation: D[n][edge] = sum_k W^T[n][k] * X^T[k][edge].
// 16 waves/block (1024 thr), 16 edges/wave, tile = 256 edges. 1 block/CU
// (LDS-limited) -> 4 waves/SIMD (was 2 at 512 thr / 32 edges/wave).
// No per-tile barrier: H1 staging is wave-private, weights read-only.
__global__ __launch_bounds__(1024, 4) void mlp_fused(
    const float* __restrict__ drug, const float* __restrict__ dis,
    const int* __restrict__ src, const int* __restrict__ dst,
    const float* __restrict__ W1, const float* __restrict__ b1,
    const float* __restrict__ g1, const float* __restrict__ be1,
    const float* __restrict__ W2, const float* __restrict__ b2,
    const float* __restrict__ g2, const float* __restrict__ be2,
    const float* __restrict__ W3, const float* __restrict__ b3,
    float* __restrict__ out, int E, int ntiles) {
  extern __shared__ char smem[];
  short* w1t = (short*)(smem + W1T_OFF);
  short* w2t = (short*)(smem + W2T_OFF);
  float* b1s = (float*)(smem + B1_OFF);
  float* g1s = (float*)(smem + G1_OFF);
  float* e1s = (float*)(smem + E1_OFF);
  float* b2s = (float*)(smem + B2_OFF);
  float* g2s = (float*)(smem + G2_OFF);
  float* e2s = (float*)(smem + E2_OFF);
  float* w3s = (float*)(smem + W3_OFF);
  float* b3s = (float*)(smem + B3_OFF);

  const int tid  = threadIdx.x;
  const int wave = tid >> 6;
  const int lane = tid & 63;
  const int q    = lane >> 4;   // quad (0..3)
  const int cc   = lane & 15;   // col-within-tile = edge slot
  short* h1w = (short*)(smem + H1_OFF) + wave * 2048;  // 16 rows x 128 bf16, wave-private

  const f32x4 z4 = {0.f, 0.f, 0.f, 0.f};

  // ---- one-time setup: weights fp32 -> bf16 LDS, XOR-swizzled (chunk^(row&7)) ----
  for (int i = tid * 4; i < 32768; i += 4096) {       // W1 [k=256][n=128]
    f32x4 v = *(const f32x4*)(W1 + i);
    int k = i >> 7, n0 = i & 127;
    #pragma unroll
    for (int j = 0; j < 4; ++j) {
      int n = n0 + j;
      w1t[n * 256 + ((((k >> 3) ^ (n & 7)) << 3) | (k & 7))] = f2bf(v[j]);
    }
  }
  for (int i = tid * 4; i < 8192; i += 4096) {        // W2 [k=128][n=64]
    f32x4 v = *(const f32x4*)(W2 + i);
    int k = i >> 6, n0 = i & 63;
    #pragma unroll
    for (int j = 0; j < 4; ++j) {
      int n = n0 + j;
      w2t[n * 128 + ((((k >> 3) ^ (n & 7)) << 3) | (k & 7))] = f2bf(v[j]);
    }
  }
  if (tid < 128) { b1s[tid] = b1[tid]; g1s[tid] = g1[tid]; e1s[tid] = be1[tid]; }
  else if (tid < 192) { int j = tid - 128; b2s[j] = b2[j]; g2s[j] = g2[j]; e2s[j] = be2[j]; w3s[j] = W3[j]; }
  if (tid == 256) b3s[0] = b3[0];
  __syncthreads();

  // ---- persistent loop over 256-edge tiles; waves free-run (no per-tile sync) ----
  for (int tile = blockIdx.x; tile < ntiles; tile += gridDim.x) {
    const int r  = tile * 256 + wave * 16 + cc;       // this lane's edge row
    const int rc = (r < E) ? r : (E - 1);             // clamp: safe reads, writes guarded
    const float* pd = drug + (size_t)src[rc] * 128;
    const float* pq = dis  + (size_t)dst[rc] * 128;

    // ===== layer 1: [256]->[128], K=256 (8 kb-steps), n-tiles=8 =====
    f32x4 acc1[8];
    #pragma unroll
    for (int i = 0; i < 8; ++i) acc1[i] = z4;

    #pragma unroll
    for (int kb = 0; kb < 8; ++kb) {
      const int k0 = kb * 32 + q * 8;                 // this lane's 8 contiguous k
      const float* p = (k0 < 128) ? (pd + k0) : (pq + (k0 - 128));
      f32x4 u0 = *(const f32x4*)p;
      f32x4 u1 = *(const f32x4*)(p + 4);
      bf16x8 bfr = pack8(u0, u1);
      #pragma unroll
      for (int nt = 0; nt < 8; ++nt) {
        const int n = nt * 16 + cc;
        bf16x8 af = *(const bf16x8*)(w1t + n * 256 + (((kb * 4 + q) ^ (n & 7)) << 3));
        acc1[nt] = MFMA16(af, bfr, acc1[nt]);
      }
    }

    // epilogue 1: +b1, LN over n=128, GELU, pack bf16 -> wave-private LDS (swizzled rows)
    {
      float s = 0.f, ss = 0.f;
      #pragma unroll
      for (int nt = 0; nt < 8; ++nt) {
        f32x4 bv = *(const f32x4*)(b1s + nt * 16 + q * 4);
        f32x4 xv = acc1[nt] + bv;
        acc1[nt] = xv;
        #pragma unroll
        for (int j = 0; j < 4; ++j) { s += xv[j]; ss += xv[j] * xv[j]; }
      }
      s  += __shfl_xor(s, 16);  s  += __shfl_xor(s, 32);
      ss += __shfl_xor(ss, 16); ss += __shfl_xor(ss, 32);
      float mu   = s * 0.0078125f;
      float var  = ss * 0.0078125f - mu * mu;
      var = (var > 0.f) ? var : 0.f;
      float rstd = __builtin_amdgcn_rsqf(var + 1e-5f);

      short* h1row = h1w + cc * 128;
      #pragma unroll
      for (int nt = 0; nt < 8; ++nt) {
        f32x4 gv = *(const f32x4*)(g1s + nt * 16 + q * 4);
        f32x4 ev = *(const f32x4*)(e1s + nt * 16 + q * 4);
        s16x4 pk;
        #pragma unroll
        for (int j = 0; j < 4; ++j) {
          float zz = __builtin_fmaf((acc1[nt][j] - mu) * rstd, gv[j], ev[j]);
          pk[j] = f2bf(gelu_exact(zz));
        }
        const int ch = nt * 2 + (q >> 1);             // (nt*16+q*4)>>3
        *(s16x4*)(h1row + (((ch ^ (cc & 7)) << 3) | ((q & 1) << 2))) = pk;
      }
    }
    // no barrier: same-wave LDS write->read ordering is handled by lgkmcnt

    // ===== layer 2: [128]->[64], K=128 (4 kb-steps), n2-tiles=4 =====
    f32x4 acc2[4];
    #pragma unroll
    for (int i = 0; i < 4; ++i) acc2[i] = z4;

    #pragma unroll
    for (int kb = 0; kb < 4; ++kb) {
      bf16x8 hb = *(const bf16x8*)(h1w + cc * 128 + (((kb * 4 + q) ^ (cc & 7)) << 3));
      #pragma unroll
      for (int t = 0; t < 4; ++t) {
        const int n2 = t * 16 + cc;
        bf16x8 af = *(const bf16x8*)(w2t + n2 * 128 + (((kb * 4 + q) ^ (n2 & 7)) << 3));
        acc2[t] = MFMA16(af, hb, acc2[t]);
      }
    }

    // epilogue 2: +b2, LN over n=64, GELU, dot with W3, +b3, store
    {
      const float bias3 = b3s[0];
      float s = 0.f, ss = 0.f;
      #pragma unroll
      for (int t = 0; t < 4; ++t) {
        f32x4 bv = *(const f32x4*)(b2s + t * 16 + q * 4);
        f32x4 xv = acc2[t] + bv;
        acc2[t] = xv;
        #pragma unroll
        for (int j = 0; j < 4; ++j) { s += xv[j]; ss += xv[j] * xv[j]; }
      }
      s  += __shfl_xor(s, 16);  s  += __shfl_xor(s, 32);
      ss += __shfl_xor(ss, 16); ss += __shfl_xor(ss, 32);
      float mu   = s * 0.015625f;
      float var  = ss * 0.015625f - mu * mu;
      var = (var > 0.f) ? var : 0.f;
      float rstd = __builtin_amdgcn_rsqf(var + 1e-5f);

      float dot = 0.f;
      #pragma unroll
      for (int t = 0; t < 4; ++t) {
        f32x4 gv = *(const f32x4*)(g2s + t * 16 + q * 4);
        f32x4 ev = *(const f32x4*)(e2s + t * 16 + q * 4);
        f32x4 wv = *(const f32x4*)(w3s + t * 16 + q * 4);
        #pragma unroll
        for (int j = 0; j < 4; ++j) {
          float zz = __builtin_fmaf((acc2[t][j] - mu) * rstd, gv[j], ev[j]);
          dot = __builtin_fmaf(gelu_exact(zz), wv[j], dot);
        }
      }
      dot += __shfl_xor(dot, 16); dot += __shfl_xor(dot, 32);
      if (q == 0 && r < E) out[r] = dot + bias3;
    }
  }
}

extern "C" void kernel_launch(void* const* d_in, const int* in_sizes, int n_in,
                              void* d_out, int out_size, void* d_ws, size_t ws_size,
                              hipStream_t stream) {
  const float* drug = (const float*)d_in[0];
  const float* dis  = (const float*)d_in[1];
  const int*   src  = (const int*)d_in[2];
  const int*   dst  = (const int*)d_in[3];
  const float* W1   = (const float*)d_in[4];
  const float* b1   = (const float*)d_in[5];
  const float* g1   = (const float*)d_in[6];
  const float* be1  = (const float*)d_in[7];
  const float* W2   = (const float*)d_in[8];
  const float* b2   = (const float*)d_in[9];
  const float* g2   = (const float*)d_in[10];
  const float* be2  = (const float*)d_in[11];
  const float* W3   = (const float*)d_in[12];
  const float* b3   = (const float*)d_in[13];
  float* out = (float*)d_out;

  const int E = in_sizes[2];
  const int ntiles = (E + 255) / 256;

  // opt-in to >64KB dynamic LDS (idempotent; host-side, capture-safe)
  (void)hipFuncSetAttribute((const void*)mlp_fused,
                            hipFuncAttributeMaxDynamicSharedMemorySize, SMEM_BYTES);

  int grid = 256;               // persistent: 1 block/CU (LDS-limited), amortizes weight staging
  if (ntiles < grid) grid = ntiles;
  mlp_fused<<<dim3(grid), dim3(1024), SMEM_BYTES, stream>>>(
      drug, dis, src, dst, W1, b1, g1, be1, W2, b2, g2, be2, W3, b3, out, E, ntiles);
}